// Round 2
// baseline (233.365 us; speedup 1.0000x reference)
//
#include <hip/hip_runtime.h>

#define DIM 512
#define WAVE 64
#define WPB 4                        // waves per block
#define RPW 4                        // rows per wave (16 lanes per row)
#define BLOCK (WAVE * WPB)
#define ROWS_PER_BLOCK (WPB * RPW)   // 16
#define LPR 16                       // lanes per row
#define EPL (DIM / LPR)              // elems per lane = 32
#define F4PL (EPL / 4)               // float4 per lane = 8

// ds_swizzle BitMode: offset = (xor<<10)|(or<<5)|and. and=0x1f, or=0, xor=m.
// xor in {1,2,4,8} stays within each 16-lane group (and within 32-lane halves,
// which is all ds_swizzle can address) -> 4-stage butterfly per 16-lane row.
#define SWZF(v, m) __int_as_float(__builtin_amdgcn_ds_swizzle(__float_as_int(v), ((m) << 10) | 0x1f))
#define SWZI(v, m) __builtin_amdgcn_ds_swizzle((v), ((m) << 10) | 0x1f)

__global__ __launch_bounds__(BLOCK) void sparsemax_kernel(
    const float* __restrict__ x, float* __restrict__ out, int batch) {
    const int wid  = threadIdx.x >> 6;
    const int lane = threadIdx.x & 63;
    const int g    = lane >> 4;      // which row of this wave's 4
    const int sub  = lane & 15;      // lane within the row
    const int row  = blockIdx.x * ROWS_PER_BLOCK + wid * RPW + g;
    if (row >= batch) return;        // whole 16-lane group exits together

    // ---- load: 8x float4 per lane, stride 16 float4 (256B segments, coalesced)
    const float4* xr = reinterpret_cast<const float4*>(x) + (size_t)row * (DIM / 4);
    float z[EPL];
#pragma unroll
    for (int i = 0; i < F4PL; ++i) {
        float4 v = xr[sub + i * LPR];
        z[4 * i + 0] = v.x; z[4 * i + 1] = v.y;
        z[4 * i + 2] = v.z; z[4 * i + 3] = v.w;
    }
    // Pin every element into a VGPR. Round-1 counters showed VGPR_Count=24:
    // the backend re-issued these (loop-invariant) loads inside the Michelot
    // loop instead of keeping z[] resident -> latency-bound L3 re-reads at
    // 82 us/dispatch. An empty asm with "+v" makes each value an opaque
    // register def the compiler cannot rematerialize or sink. 0 instructions.
#pragma unroll
    for (int j = 0; j < EPL; ++j) asm("" : "+v"(z[j]));

    // ---- row max (per-lane tree, then 4-stage 16-lane butterfly)
    float m = fmaxf(z[0], z[1]);
#pragma unroll
    for (int j = 2; j < EPL; ++j) m = fmaxf(m, z[j]);
    m = fmaxf(m, SWZF(m, 1));
    m = fmaxf(m, SWZF(m, 2));
    m = fmaxf(m, SWZF(m, 4));
    m = fmaxf(m, SWZF(m, 8));

    // ---- Michelot / fixed-point: tau' = (S-1)/K over {z > tau}.
    // tau0 = max-1 is a valid lower bound (p_max <= 1); sets shrink, tau
    // monotone up, finite exact convergence (K stable <=> fixed point).
    // Converged rows recompute a bitwise-identical tau, so running the wave
    // until ALL 4 rows are stable is harmless.
    float tau = m - 1.0f;
    int kprev = 0;
    for (int it = 0; it < 32; ++it) {
        float S = 0.f;
        int   K = 0;
#pragma unroll
        for (int j = 0; j < EPL; ++j) {
            const bool in = z[j] > tau;
            S += in ? z[j] : 0.f;
            K += in ? 1 : 0;
        }
        // two independent 4-stage butterflies (S float, K int), interleaved
        // so their LDS latencies overlap
        { float s1 = SWZF(S, 1); int k1 = SWZI(K, 1); S += s1; K += k1; }
        { float s1 = SWZF(S, 2); int k1 = SWZI(K, 2); S += s1; K += k1; }
        { float s1 = SWZF(S, 4); int k1 = SWZI(K, 4); S += s1; K += k1; }
        { float s1 = SWZF(S, 8); int k1 = SWZI(K, 8); S += s1; K += k1; }
        if (__all(K == kprev)) break;  // all 4 rows stable -> fixed point
        kprev = K;
        tau = (S - 1.0f) * __builtin_amdgcn_rcpf((float)K);  // K >= 1 always
    }

    // ---- epilogue: out = max(0, z - tau)
    float4* orow = reinterpret_cast<float4*>(out) + (size_t)row * (DIM / 4);
#pragma unroll
    for (int i = 0; i < F4PL; ++i) {
        float4 v;
        v.x = fmaxf(0.f, z[4 * i + 0] - tau);
        v.y = fmaxf(0.f, z[4 * i + 1] - tau);
        v.z = fmaxf(0.f, z[4 * i + 2] - tau);
        v.w = fmaxf(0.f, z[4 * i + 3] - tau);
        orow[sub + i * LPR] = v;
    }
}

extern "C" void kernel_launch(void* const* d_in, const int* in_sizes, int n_in,
                              void* d_out, int out_size, void* d_ws, size_t ws_size,
                              hipStream_t stream) {
    const float* x = (const float*)d_in[0];
    float* out     = (float*)d_out;
    const int batch = in_sizes[0] / DIM;  // 65536
    const int grid  = (batch + ROWS_PER_BLOCK - 1) / ROWS_PER_BLOCK;
    sparsemax_kernel<<<grid, BLOCK, 0, stream>>>(x, out, batch);
}

// Round 3
// 226.908 us; speedup vs baseline: 1.0285x; 1.0285x over previous
//
#include <hip/hip_runtime.h>

#define DIM 512
#define WAVE 64
#define WPB 4                        // waves per block
#define RPW 2                        // rows per wave (32 lanes per row)
#define BLOCK (WAVE * WPB)
#define ROWS_PER_BLOCK (WPB * RPW)   // 8
#define LPR 32                       // lanes per row
#define EPL (DIM / LPR)              // elems per lane = 16 -> ~40 VGPR total:
                                     // stays under the 64-VGPR / 8-waves-per-SIMD
                                     // tier, so the backend keeps z[] resident
                                     // (round 1/2: z[32] -> demoted, VGPR=24,
                                     // latency-bound re-reads, 82us)
#define F4PL (EPL / 4)               // float4 per lane = 4

// ds_swizzle BitMode: offset = (xor<<10)|(or<<5)|and. and=0x1f, or=0, xor=m.
// xor in {1,2,4,8,16} stays within each 32-lane half -> 5-stage butterfly per
// 32-lane row, no ds_bpermute needed anywhere.
#define SWZF(v, m) __int_as_float(__builtin_amdgcn_ds_swizzle(__float_as_int(v), ((m) << 10) | 0x1f))
#define SWZI(v, m) __builtin_amdgcn_ds_swizzle((v), ((m) << 10) | 0x1f)

__global__ __launch_bounds__(BLOCK) void sparsemax_kernel(
    const float* __restrict__ x, float* __restrict__ out, int batch) {
    const int wid  = threadIdx.x >> 6;
    const int lane = threadIdx.x & 63;
    const int g    = lane >> 5;      // which row of this wave's 2
    const int sub  = lane & 31;      // lane within the row
    const int row  = blockIdx.x * ROWS_PER_BLOCK + wid * RPW + g;
    if (row >= batch) return;        // whole 32-lane half exits together

    // ---- load: 4x float4 per lane, back-to-back (max MLP), 512B segments
    const float4* xr = reinterpret_cast<const float4*>(x) + (size_t)row * (DIM / 4);
    float z[EPL];
#pragma unroll
    for (int i = 0; i < F4PL; ++i) {
        float4 v = xr[sub + i * LPR];
        z[4 * i + 0] = v.x; z[4 * i + 1] = v.y;
        z[4 * i + 2] = v.z; z[4 * i + 3] = v.w;
    }
#pragma unroll
    for (int j = 0; j < EPL; ++j) asm("" : "+v"(z[j]));  // residency insurance

    // ---- row max AND row sum in one pass (independent butterflies, same
    //      LDS stages -> latencies overlap; sum buys a tighter tau0 below)
    float m = fmaxf(z[0], z[1]);
    float s = z[0] + z[1];
#pragma unroll
    for (int j = 2; j < EPL; ++j) { m = fmaxf(m, z[j]); s += z[j]; }
    { float m1 = SWZF(m, 1);  float s1 = SWZF(s, 1);  m = fmaxf(m, m1); s += s1; }
    { float m1 = SWZF(m, 2);  float s1 = SWZF(s, 2);  m = fmaxf(m, m1); s += s1; }
    { float m1 = SWZF(m, 4);  float s1 = SWZF(s, 4);  m = fmaxf(m, m1); s += s1; }
    { float m1 = SWZF(m, 8);  float s1 = SWZF(s, 8);  m = fmaxf(m, m1); s += s1; }
    { float m1 = SWZF(m, 16); float s1 = SWZF(s, 16); m = fmaxf(m, m1); s += s1; }

    // ---- Michelot / fixed-point: tau' = (S-1)/K over {z > tau}.
    // tau0 = max(m-1, (sum-1)/512): both are lower bounds of tau* (p_max<=1
    // gives m-1; Michelot's full-set start gives (sum-1)/n), so their max is
    // a valid, tighter start -> typically saves one reduce iteration.
    // For any t <= tau*: {z>t} contains the support and (S-1)/K <= tau*
    // (extra elements average <= tau*), fixed point iff set == support.
    float tau = fmaxf(m - 1.0f, (s - 1.0f) * (1.0f / (float)DIM));
    int kprev = 0;
    for (int it = 0; it < 32; ++it) {
        float S = 0.f;
        int   K = 0;
#pragma unroll
        for (int j = 0; j < EPL; ++j) {
            const bool in = z[j] > tau;
            S += in ? z[j] : 0.f;
            K += in ? 1 : 0;
        }
        // two independent 5-stage butterflies (S float, K int), interleaved
        { float s1 = SWZF(S, 1);  int k1 = SWZI(K, 1);  S += s1; K += k1; }
        { float s1 = SWZF(S, 2);  int k1 = SWZI(K, 2);  S += s1; K += k1; }
        { float s1 = SWZF(S, 4);  int k1 = SWZI(K, 4);  S += s1; K += k1; }
        { float s1 = SWZF(S, 8);  int k1 = SWZI(K, 8);  S += s1; K += k1; }
        { float s1 = SWZF(S, 16); int k1 = SWZI(K, 16); S += s1; K += k1; }
        if (__all(K == kprev)) break;  // both rows stable -> fixed point
        kprev = K;
        tau = (S - 1.0f) * __builtin_amdgcn_rcpf((float)K);  // K >= 1 always
    }

    // ---- epilogue: out = max(0, z - tau)
    float4* orow = reinterpret_cast<float4*>(out) + (size_t)row * (DIM / 4);
#pragma unroll
    for (int i = 0; i < F4PL; ++i) {
        float4 v;
        v.x = fmaxf(0.f, z[4 * i + 0] - tau);
        v.y = fmaxf(0.f, z[4 * i + 1] - tau);
        v.z = fmaxf(0.f, z[4 * i + 2] - tau);
        v.w = fmaxf(0.f, z[4 * i + 3] - tau);
        orow[sub + i * LPR] = v;
    }
}

extern "C" void kernel_launch(void* const* d_in, const int* in_sizes, int n_in,
                              void* d_out, int out_size, void* d_ws, size_t ws_size,
                              hipStream_t stream) {
    const float* x = (const float*)d_in[0];
    float* out     = (float*)d_out;
    const int batch = in_sizes[0] / DIM;  // 65536
    const int grid  = (batch + ROWS_PER_BLOCK - 1) / ROWS_PER_BLOCK;
    sparsemax_kernel<<<grid, BLOCK, 0, stream>>>(x, out, batch);
}

// Round 4
// 225.098 us; speedup vs baseline: 1.0367x; 1.0080x over previous
//
#include <hip/hip_runtime.h>

#define DIM 512
#define WAVE 64
#define WPB 4
#define BLOCK (WAVE * WPB)

// ---- DS-free 64-lane butterflies -------------------------------------------
// Stages 1,2,4,8: DPP (quad_perm xor1/xor2, row_ror:4/8) — pure VALU.
// Stages 16,32: gfx950 v_permlane16/32_swap_b32. Seeding BOTH operands with x
// and combining t,u afterwards yields the pairwise-exchange reduce in every
// lane (any half-swap semantics + commutativity), no cndmask needed.
// Entire 64-lane all-reduce: ~10 VALU ops, ~60 cyc, zero DS traffic
// (vs 6 dependent ds_swizzle/bpermute at ~120 cyc each in the 66us version).

#define DPPF(x, ctrl) __int_as_float(__builtin_amdgcn_update_dpp( \
    __float_as_int(x), __float_as_int(x), (ctrl), 0xf, 0xf, false))

__device__ __forceinline__ float red16_sum(float x) {
    x += DPPF(x, 0xB1);   // quad_perm(1,0,3,2): xor1
    x += DPPF(x, 0x4E);   // quad_perm(2,3,0,1): xor2
    x += DPPF(x, 0x124);  // row_ror:4
    x += DPPF(x, 0x128);  // row_ror:8  -> 16-lane group sums
    return x;
}
__device__ __forceinline__ float red16_max(float x) {
    x = fmaxf(x, DPPF(x, 0xB1));
    x = fmaxf(x, DPPF(x, 0x4E));
    x = fmaxf(x, DPPF(x, 0x124));
    x = fmaxf(x, DPPF(x, 0x128));
    return x;
}
__device__ __forceinline__ float xswap16_sum(float x) {
    float t = x, u = x;
    asm("" : "+v"(u));  // make u a distinct vreg so the swap can't coalesce t,u
    asm("v_permlane16_swap_b32 %0, %1" : "+v"(t), "+v"(u));
    return t + u;
}
__device__ __forceinline__ float xswap32_sum(float x) {
    float t = x, u = x;
    asm("" : "+v"(u));
    asm("v_permlane32_swap_b32 %0, %1" : "+v"(t), "+v"(u));
    return t + u;
}
__device__ __forceinline__ float xswap16_max(float x) {
    float t = x, u = x;
    asm("" : "+v"(u));
    asm("v_permlane16_swap_b32 %0, %1" : "+v"(t), "+v"(u));
    return fmaxf(t, u);
}
__device__ __forceinline__ float xswap32_max(float x) {
    float t = x, u = x;
    asm("" : "+v"(u));
    asm("v_permlane32_swap_b32 %0, %1" : "+v"(t), "+v"(u));
    return fmaxf(t, u);
}

__device__ __forceinline__ float allred_sum(float x) {
    return xswap32_sum(xswap16_sum(red16_sum(x)));
}
__device__ __forceinline__ float allred_max(float x) {
    return xswap32_max(xswap16_max(red16_max(x)));
}

__global__ __launch_bounds__(BLOCK) void sparsemax_kernel(
    const float* __restrict__ x, float* __restrict__ out, int batch) {
    // Round-0 structure: 1 row per 64-lane wave, z[8]/lane (the only layout
    // the backend keeps register-resident; z[16]/z[32] were demoted ->
    // VGPR_Count 16/24, latency-bound re-reads, 80-85us).
    const int row  = blockIdx.x * WPB + (threadIdx.x >> 6);
    const int lane = threadIdx.x & 63;
    if (row >= batch) return;

    const float4* xr = reinterpret_cast<const float4*>(x) + (size_t)row * (DIM / 4);
    float4 a = xr[lane];
    float4 b = xr[lane + WAVE];
    float z[8] = {a.x, a.y, a.z, a.w, b.x, b.y, b.z, b.w};

    // ---- tau0 = max - 1 (valid lower bound: p_max <= 1)
    float m = fmaxf(fmaxf(fmaxf(z[0], z[1]), fmaxf(z[2], z[3])),
                    fmaxf(fmaxf(z[4], z[5]), fmaxf(z[6], z[7])));
    m = allred_max(m);
    float tau = m - 1.0f;

    // ---- Michelot fixed point: tau' = (S-1)/K over {z > tau}; sets nested &
    // shrinking from a lower bound, K stable <=> fixed point (exact, finite).
    // K via ballots (scalar pipe, wave-uniform) -- no int reduce needed.
    int kprev = 0;
    for (int it = 0; it < 32; ++it) {
        float S = 0.f;
        int   K = 0;
#pragma unroll
        for (int j = 0; j < 8; ++j) {
            const bool in = z[j] > tau;
            S += in ? z[j] : 0.f;
            K += (int)__popcll(__ballot(in));
        }
        S = allred_sum(S);
        if (K == kprev) break;  // wave-uniform branch
        kprev = K;
        tau = (S - 1.0f) * __builtin_amdgcn_rcpf((float)K);  // K >= 1 always
    }

    // ---- epilogue: out = max(0, z - tau)
    float4 oa, ob;
    oa.x = fmaxf(0.f, z[0] - tau);
    oa.y = fmaxf(0.f, z[1] - tau);
    oa.z = fmaxf(0.f, z[2] - tau);
    oa.w = fmaxf(0.f, z[3] - tau);
    ob.x = fmaxf(0.f, z[4] - tau);
    ob.y = fmaxf(0.f, z[5] - tau);
    ob.z = fmaxf(0.f, z[6] - tau);
    ob.w = fmaxf(0.f, z[7] - tau);
    float4* orow = reinterpret_cast<float4*>(out) + (size_t)row * (DIM / 4);
    orow[lane]        = oa;
    orow[lane + WAVE] = ob;
}

extern "C" void kernel_launch(void* const* d_in, const int* in_sizes, int n_in,
                              void* d_out, int out_size, void* d_ws, size_t ws_size,
                              hipStream_t stream) {
    const float* x = (const float*)d_in[0];
    float* out     = (float*)d_out;
    const int batch = in_sizes[0] / DIM;  // 65536
    const int grid  = (batch + WPB - 1) / WPB;
    sparsemax_kernel<<<grid, BLOCK, 0, stream>>>(x, out, batch);
}